// Round 5
// baseline (94.971 us; speedup 1.0000x reference)
//
#include <hip/hip_runtime.h>

typedef _Float16 half_t;
typedef _Float16 halfv8 __attribute__((ext_vector_type(8)));
typedef _Float16 halfv4 __attribute__((ext_vector_type(4)));
typedef float    floatv4 __attribute__((ext_vector_type(4)));
typedef unsigned int uint;
typedef uint uintv4 __attribute__((ext_vector_type(4)));

#define NODES 32
#define FIN   128
#define EPG   512
#define NBS   4096
#define ETOT  (NBS*EPG)
#define HID   1024
#define KDIM  4096   // FIN*NODES
#define NCLS  10
#define YPITCH 36

// lin1 GEMM geometry
#define BM 256
#define BN 256
#define BK 64          // halves per LDS row (128 B)
#define KS 4           // split-K factor
#define KSLEN (KDIM/KS) // 1024
#define NT (KSLEN/BK)   // 16 K-tiles per block

// async global->LDS, 16B per lane (dest = wave-uniform base + lane*16)
#define GLDS16(g, l)                                                        \
  __builtin_amdgcn_global_load_lds(                                         \
      (const __attribute__((address_space(1))) unsigned int*)(g),           \
      (__attribute__((address_space(3))) unsigned int*)(l), 16, 0, 0)

// ---------------------------------------------------------------------------
// prep: lin1_w fp32 [o][f*32+n] -> fp16 permuted [o][n*128+f];
// blocks also fold in the gconv_w fp32->fp16 conversion (16 elems/block).
__global__ __launch_bounds__(256) void prep_w1(const float* __restrict__ w1,
                                               half_t* __restrict__ w1p,
                                               const float* __restrict__ gw,
                                               half_t* __restrict__ gw16) {
  __shared__ float tmp[FIN * 33];
  const int o = blockIdx.x, t = threadIdx.x;
  if (t < 16) {
    const int i = o * 16 + t;   // 1024 blocks x 16 = 16384 = FIN*FIN
    gw16[i] = (half_t)gw[i];
  }
  const floatv4* src = (const floatv4*)(w1 + (size_t)o * KDIM);
  for (int i = t; i < KDIM / 4; i += 256) {
    floatv4 v = src[i];
    const int f = i >> 3;
    const int n = (i & 7) * 4;
#pragma unroll
    for (int q = 0; q < 4; ++q) tmp[f * 33 + n + q] = v[q];
  }
  __syncthreads();
  half_t* dst = w1p + (size_t)o * KDIM;
  for (int i = t; i < KDIM; i += 256) {
    const int n = i >> 7, f = i & 127;
    dst[i] = (half_t)tmp[f * 33 + n];
  }
}

// ---------------------------------------------------------------------------
// Fused GIN conv via linearity: H_g = relu( (I + C_g) @ (x_g @ W^T) + b )
// v2: barrier-free. W fragments read straight from global (L1/L2-resident
// 32 KB); only per-wave LDS (Yt bounce + histogram) -> 45 KB, 3 blocks/CU.
__global__ __launch_bounds__(256, 3) void gin_fused(
    const float* __restrict__ x, const int* __restrict__ ei,
    const half_t* __restrict__ gw16, const float* __restrict__ gb,
    half_t* __restrict__ H) {
  __shared__ __attribute__((aligned(16))) half_t Yt[4][FIN * YPITCH];  // 36864 B
  __shared__ __attribute__((aligned(16))) uint  cnt[4][512];           //  8192 B

  const int t = threadIdx.x, w = t >> 6, l = t & 63;
  const int lr = l & 15, lk = l >> 4;
  const int g = blockIdx.x * 4 + w;

  // (a) this wave's x tile (32x128 fp32) -> registers
  const float* xg = x + (size_t)g * (NODES * FIN);
  floatv4 xr[2][4][2];
#pragma unroll
  for (int mt = 0; mt < 2; ++mt)
#pragma unroll
    for (int kk = 0; kk < 4; ++kk) {
      const float* p = xg + (mt * 16 + lr) * FIN + kk * 32 + lk * 8;
      xr[mt][kk][0] = *(const floatv4*)p;
      xr[mt][kk][1] = *(const floatv4*)(p + 4);
    }
  // (b) this wave's edges (contiguous per graph; local id = idx & 31)
  const int* sp = ei + (size_t)g * EPG;
  const int* dp = ei + (size_t)ETOT + (size_t)g * EPG;
  uintv4 s0 = *(const uintv4*)(sp + l * 8);
  uintv4 s1 = *(const uintv4*)(sp + l * 8 + 4);
  uintv4 d0 = *(const uintv4*)(dp + l * 8);
  uintv4 d1 = *(const uintv4*)(dp + l * 8 + 4);

  // (c) zero this wave's histogram (wave-private: no barrier needed)
  {
    uintv4* c4 = (uintv4*)cnt[w];
    uintv4 z = {0, 0, 0, 0};
    c4[l] = z;
    c4[l + 64] = z;
  }
  // (d) histogram: cnt16[dst*32+src] += 1 (packed two u16 per u32)
#pragma unroll
  for (int q = 0; q < 4; ++q) {
    uint p0 = (d0[q] & 31) * 32 + (s0[q] & 31);
    atomicAdd(&cnt[w][p0 >> 1], 1u << ((p0 & 1) * 16));
    uint p1 = (d1[q] & 31) * 32 + (s1[q] & 31);
    atomicAdd(&cnt[w][p1 >> 1], 1u << ((p1 & 1) * 16));
  }

  // (e) convert x to fp16 A-fragments
  halfv8 af[2][4];
#pragma unroll
  for (int mt = 0; mt < 2; ++mt)
#pragma unroll
    for (int kk = 0; kk < 4; ++kk) {
      halfv8 h;
#pragma unroll
      for (int q = 0; q < 4; ++q) {
        h[q]     = (half_t)xr[mt][kk][0][q];
        h[q + 4] = (half_t)xr[mt][kk][1][q];
      }
      af[mt][kk] = h;
    }

  // (f) MFMA1: Z[j][o] = sum_f x[j][f] W[o][f]; B-frags from global (L1/L2)
  floatv4 acc[2][8] = {};
#pragma unroll
  for (int kk = 0; kk < 4; ++kk) {
    halfv8 bfk[8];
#pragma unroll
    for (int nt = 0; nt < 8; ++nt)
      bfk[nt] = *(const halfv8*)(gw16 + (nt * 16 + lr) * FIN + kk * 32 + lk * 8);
#pragma unroll
    for (int nt = 0; nt < 8; ++nt)
#pragma unroll
      for (int mt = 0; mt < 2; ++mt)
        acc[mt][nt] = __builtin_amdgcn_mfma_f32_16x16x32_f16(af[mt][kk], bfk[nt],
                                                             acc[mt][nt], 0, 0, 0);
  }

  // (g) bounce Z transposed into this wave's LDS: Yt[o][j]
  half_t* yw = Yt[w];
#pragma unroll
  for (int mt = 0; mt < 2; ++mt)
#pragma unroll
    for (int nt = 0; nt < 8; ++nt) {
      halfv4 h = {(half_t)acc[mt][nt][0], (half_t)acc[mt][nt][1],
                  (half_t)acc[mt][nt][2], (half_t)acc[mt][nt][3]};
      *(halfv4*)&yw[(nt * 16 + lr) * YPITCH + mt * 16 + lk * 4] = h;
    }

  // (h) build M' = I + C fragments from the histogram (u16 reads, same wave)
  const unsigned short* c16 = (const unsigned short*)cnt[w];
  halfv8 am[2];
#pragma unroll
  for (int mt = 0; mt < 2; ++mt) {
    const int i = mt * 16 + lr;
#pragma unroll
    for (int q = 0; q < 8; ++q) {
      const int j = lk * 8 + q;
      float c = (float)c16[i * 32 + j] + ((j == i) ? 1.f : 0.f);
      am[mt][q] = (half_t)c;
    }
  }

  // (i) MFMA2: H[i][o] = sum_j M'[i][j] Z[j][o]   (K=32, single step)
  floatv4 acc2[2][8] = {};
#pragma unroll
  for (int nt = 0; nt < 8; ++nt) {
    halfv8 bf = *(const halfv8*)&yw[(nt * 16 + lr) * YPITCH + lk * 8];
#pragma unroll
    for (int mt = 0; mt < 2; ++mt)
      acc2[mt][nt] = __builtin_amdgcn_mfma_f32_16x16x32_f16(am[mt], bf,
                                                            acc2[mt][nt], 0, 0, 0);
  }

  // (j) bias + relu + store H node-major: H[g][j*128 + o]
  half_t* Hg = H + (size_t)g * KDIM;
#pragma unroll
  for (int nt = 0; nt < 8; ++nt) {
    const float bias = gb[nt * 16 + lr];
#pragma unroll
    for (int mt = 0; mt < 2; ++mt)
#pragma unroll
      for (int q = 0; q < 4; ++q) {
        const int m = mt * 16 + lk * 4 + q;
        const float v = acc2[mt][nt][q] + bias;
        Hg[m * FIN + nt * 16 + lr] = (half_t)(v > 0.f ? v : 0.f);
      }
  }
}

// ---------------------------------------------------------------------------
// lin1 GEMM, 256x256 tile, BK=64, 8 waves, split-K=4. (unchanged from r4)
__global__ __launch_bounds__(512, 2) void lin1_gemm(
    const half_t* __restrict__ A, const half_t* __restrict__ B,
    half_t* __restrict__ Cbase) {
  __shared__ __attribute__((aligned(16))) half_t As[2][BM * BK];  // 64 KB
  __shared__ __attribute__((aligned(16))) half_t Bs[2][BN * BK];  // 64 KB

  const int t = threadIdx.x;
  const int orig = blockIdx.x;
  const int wg = (orig & 7) * 32 + (orig >> 3);
  const int mt = wg & 15, rest = wg >> 4;
  const int nt_ = rest & 3, ks = rest >> 2;
  const int m0 = mt * BM, n0 = nt_ * BN, k0 = ks * KSLEN;

  const half_t* gA[4];
  const half_t* gB[4];
#pragma unroll
  for (int j = 0; j < 4; ++j) {
    const int L = t + j * 512;
    const int r = L >> 3;
    const int c = (L & 7) ^ (r & 7);
    gA[j] = A + (size_t)(m0 + r) * KDIM + k0 + c * 8;
    gB[j] = B + (size_t)(n0 + r) * KDIM + k0 + c * 8;
  }

#define STAGE(buf, koff)                                                    \
  {                                                                         \
    _Pragma("unroll")                                                       \
    for (int j = 0; j < 4; ++j)                                             \
      GLDS16(gA[j] + (koff), &As[buf][(t + j * 512) * 8]);                  \
    _Pragma("unroll")                                                       \
    for (int j = 0; j < 4; ++j)                                             \
      GLDS16(gB[j] + (koff), &Bs[buf][(t + j * 512) * 8]);                  \
  }

  const int w = t >> 6, l = t & 63, lr = l & 15, lk = l >> 4;
  const int wm = (w >> 2) * 128, wn = (w & 3) * 64;

  floatv4 acc[8][4] = {};

  STAGE(0, 0)
  STAGE(1, BK)
  asm volatile("s_waitcnt vmcnt(8)" ::: "memory");
  __builtin_amdgcn_s_barrier();

  for (int kt = 0; kt < NT; ++kt) {
    const int cur = kt & 1;
    const half_t* as = As[cur];
    const half_t* bs = Bs[cur];
#pragma unroll
    for (int ksb = 0; ksb < 2; ++ksb) {
      halfv8 bf[4], af[8];
#pragma unroll
      for (int nf = 0; nf < 4; ++nf) {
        const int row = wn + nf * 16 + lr;
        const int ch = (ksb * 4 + lk) ^ (row & 7);
        bf[nf] = *(const halfv8*)&bs[row * BK + ch * 8];
      }
#pragma unroll
      for (int mf = 0; mf < 8; ++mf) {
        const int row = wm + mf * 16 + lr;
        const int ch = (ksb * 4 + lk) ^ (row & 7);
        af[mf] = *(const halfv8*)&as[row * BK + ch * 8];
      }
      __builtin_amdgcn_s_setprio(1);
#pragma unroll
      for (int mf = 0; mf < 8; ++mf)
#pragma unroll
        for (int nf = 0; nf < 4; ++nf)
          acc[mf][nf] = __builtin_amdgcn_mfma_f32_16x16x32_f16(
              af[mf], bf[nf], acc[mf][nf], 0, 0, 0);
      __builtin_amdgcn_s_setprio(0);
    }
    __builtin_amdgcn_s_barrier();
    const int src = (kt + 2 < NT) ? (kt + 2) : 0;  // dummy keeps vmcnt uniform
    STAGE(cur, src * BK)
    asm volatile("s_waitcnt vmcnt(8)" ::: "memory");
    __builtin_amdgcn_s_barrier();
  }

  half_t* C = Cbase + (size_t)ks * ((size_t)NBS * HID);
#pragma unroll
  for (int mf = 0; mf < 8; ++mf)
#pragma unroll
    for (int nf = 0; nf < 4; ++nf) {
      const int n = n0 + wn + nf * 16 + lr;
#pragma unroll
      for (int q = 0; q < 4; ++q) {
        const int m = m0 + wm + mf * 16 + lk * 4 + q;
        C[(size_t)m * HID + n] = (half_t)acc[mf][nf][q];
      }
    }
#undef STAGE
}

// ---------------------------------------------------------------------------
// head: hidden = relu(sum_ks C[ks] + b1); logits = hidden @ w2^T + b2; softmax
__global__ __launch_bounds__(256) void head(
    const half_t* __restrict__ Cb, const float* __restrict__ b1,
    const float* __restrict__ w2, const float* __restrict__ b2,
    float* __restrict__ out) {
  __shared__ __attribute__((aligned(16))) float w2s[NCLS * HID];
  const int t = threadIdx.x;
  {
    const floatv4* s4 = (const floatv4*)w2;
    floatv4* d4 = (floatv4*)w2s;
    for (int i = t; i < (NCLS * HID) / 4; i += 256) d4[i] = s4[i];
  }
  __syncthreads();
  const int w = t >> 6, l = t & 63;
  const int row = blockIdx.x * 4 + w;

  float r[16];
#pragma unroll
  for (int jj = 0; jj < 4; ++jj) {
    floatv4 bb = *(const floatv4*)&b1[jj * 256 + l * 4];
    float s[4] = {bb[0], bb[1], bb[2], bb[3]};
#pragma unroll
    for (int p = 0; p < KS; ++p) {
      const half_t* cp = Cb + (size_t)p * ((size_t)NBS * HID) + (size_t)row * HID;
      halfv4 u = *(const halfv4*)&cp[jj * 256 + l * 4];
#pragma unroll
      for (int q = 0; q < 4; ++q) s[q] += (float)u[q];
    }
#pragma unroll
    for (int q = 0; q < 4; ++q) r[jj * 4 + q] = s[q] > 0.f ? s[q] : 0.f;
  }
  float lg[10];
#pragma unroll
  for (int c = 0; c < NCLS; ++c) {
    float p = 0.f;
#pragma unroll
    for (int jj = 0; jj < 4; ++jj) {
      floatv4 wv = *(const floatv4*)&w2s[c * HID + jj * 256 + l * 4];
      p += r[jj * 4 + 0] * wv[0] + r[jj * 4 + 1] * wv[1] +
           r[jj * 4 + 2] * wv[2] + r[jj * 4 + 3] * wv[3];
    }
#pragma unroll
    for (int off = 32; off >= 1; off >>= 1) p += __shfl_xor(p, off);
    lg[c] = p + b2[c];
  }
  float mx = lg[0];
#pragma unroll
  for (int c = 1; c < NCLS; ++c) mx = fmaxf(mx, lg[c]);
  float sum = 0.f;
#pragma unroll
  for (int c = 0; c < NCLS; ++c) { lg[c] = __expf(lg[c] - mx); sum += lg[c]; }
  const float inv = 1.f / sum;
  float myv = 0.f;
#pragma unroll
  for (int c = 0; c < NCLS; ++c) myv = (l == c) ? lg[c] * inv : myv;
  if (l < NCLS) out[(size_t)row * NCLS + l] = myv;
}

// ---------------------------------------------------------------------------
extern "C" void kernel_launch(void* const* d_in, const int* in_sizes, int n_in,
                              void* d_out, int out_size, void* d_ws, size_t ws_size,
                              hipStream_t stream) {
  (void)in_sizes; (void)n_in; (void)out_size; (void)ws_size;
  const float* x  = (const float*)d_in[0];
  const int*   ei = (const int*)d_in[1];
  const float* gw = (const float*)d_in[2];
  const float* gb = (const float*)d_in[3];
  const float* w1 = (const float*)d_in[4];
  const float* b1 = (const float*)d_in[5];
  const float* w2 = (const float*)d_in[6];
  const float* b2 = (const float*)d_in[7];
  float* out = (float*)d_out;

  char* ws = (char*)d_ws;
  half_t* H    = (half_t*)(ws);                        // 32 MB
  half_t* w1p  = (half_t*)(ws + 33554432);             //  8 MB
  half_t* C    = (half_t*)(ws + 33554432 + 8388608);   // KS x 8 MB = 32 MB
  half_t* gw16 = (half_t*)(ws + 33554432 + 8388608 + (size_t)KS * NBS * HID * 2);

  prep_w1  <<<dim3(HID),     dim3(256), 0, stream>>>(w1, w1p, gw, gw16);
  gin_fused<<<dim3(NBS / 4), dim3(256), 0, stream>>>(x, ei, gw16, gb, H);
  lin1_gemm<<<dim3(16 * 4 * KS), dim3(512), 0, stream>>>(H, w1p, C);
  head     <<<dim3(NBS / 4), dim3(256), 0, stream>>>(C, b1, w2, b2, out);
}